// Round 1
// baseline (142.890 us; speedup 1.0000x reference)
//
#include <hip/hip_runtime.h>
#include <hip/hip_bf16.h>

#define B_SZ 2048
#define H_SZ 200
#define BH (B_SZ * H_SZ)
#define EMB 128
#define HID 256
#define KP 160          // padded K (130 real + bias-free pad)
#define LDA 168         // LDS row stride in ushorts (bank-conflict pad)
#define BM 64           // rows per block

typedef short bf16x8 __attribute__((ext_vector_type(8)));
typedef float f32x4 __attribute__((ext_vector_type(4)));

__device__ __forceinline__ unsigned short bfc(float x) {
    // RNE float->bf16 (finite values only here)
    unsigned u = __float_as_uint(x);
    u += 0x7FFFu + ((u >> 16) & 1u);
    return (unsigned short)(u >> 16);
}

// W1 [130][256] fp32 -> W1T [256][160] bf16, zero-padded K rows 130..159
__global__ void prep_w1t(const float* __restrict__ W1, unsigned short* __restrict__ W1T) {
    int i = blockIdx.x * 256 + threadIdx.x;      // 256*160 total
    int n = i / KP;
    int k = i - n * KP;
    float v = (k < 130) ? W1[k * HID + n] : 0.f;
    W1T[i] = bfc(v);
}

__global__ __launch_bounds__(256) void attn_kernel(
    const int* __restrict__ history, const int* __restrict__ target,
    const float* __restrict__ td, const float* __restrict__ eh,
    const float* __restrict__ et, const unsigned short* __restrict__ W1T,
    const float* __restrict__ b1, const float* __restrict__ W2,
    const float* __restrict__ Wd, const float* __restrict__ bd,
    float* __restrict__ expA, float* __restrict__ uOut)
{
    __shared__ __align__(16) unsigned short At[BM * LDA];
    __shared__ float u_lds[BM];
    __shared__ float red[BM][4];

    const int tid = threadIdx.x;
    const int rowBase = blockIdx.x * BM;

    // ---- build A tile: inp[m][k] = h*t (k<128), dist (128,129), 0 pad ----
    {
        const int m = tid >> 2;          // row within tile
        const int q = tid & 3;           // quarter of EMB
        const int row = rowBase + m;
        const int b = row / H_SZ;
        const int idx = history[row];
        const int tgt = target[b];
        const float4* hp = (const float4*)(eh + (size_t)idx * EMB + q * 32);
        const float4* tp = (const float4*)(et + (size_t)tgt * EMB + q * 32);
        unsigned short* dst = At + m * LDA + q * 32;
        float su = 0.f;
#pragma unroll
        for (int i = 0; i < 8; ++i) {
            float4 hv = hp[i];
            float4 tv = tp[i];
            float p0 = hv.x * tv.x, p1 = hv.y * tv.y;
            float p2 = hv.z * tv.z, p3 = hv.w * tv.w;
            su += (p0 + p1) + (p2 + p3);
            unsigned v0 = (unsigned)bfc(p0) | ((unsigned)bfc(p1) << 16);
            unsigned v1 = (unsigned)bfc(p2) | ((unsigned)bfc(p3) << 16);
            *reinterpret_cast<uint2*>(dst + 4 * i) = make_uint2(v0, v1);
        }
        // u = sum_k (h*t)[k], exact fp32, reduced over the 4 threads of this row
        su += __shfl_xor(su, 1);
        su += __shfl_xor(su, 2);
        if (q == 0) {
            u_lds[m] = su;
            // dist layer: sigmoid(1000*td @ Wd + bd)
            float x0 = td[(size_t)row * 2 + 0] * 1000.f;
            float x1 = td[(size_t)row * 2 + 1] * 1000.f;
            float d0 = x0 * Wd[0] + x1 * Wd[2] + bd[0];
            float d1 = x0 * Wd[1] + x1 * Wd[3] + bd[1];
            d0 = 1.f / (1.f + expf(-d0));
            d1 = 1.f / (1.f + expf(-d1));
            At[m * LDA + 128] = bfc(d0);
            At[m * LDA + 129] = bfc(d1);
        } else if (q == 1) {
            unsigned short* z = At + m * LDA + 130;
#pragma unroll
            for (int k = 0; k < 30; ++k) z[k] = 0;
        }
    }
    __syncthreads();

    // ---- MFMA: hidden = A @ W1, 4 waves split N=256 into 64-col strips ----
    const int l  = tid & 63;
    const int w  = tid >> 6;
    const int lr = l & 15;
    const int lq = l >> 4;

    bf16x8 bfr[4][5];
    float b1v[4], w2v[4];
#pragma unroll
    for (int nt = 0; nt < 4; ++nt) {
        const int n = w * 64 + nt * 16 + lr;
        b1v[nt] = b1[n];
        w2v[nt] = W2[n];
#pragma unroll
        for (int ks = 0; ks < 5; ++ks)
            bfr[nt][ks] = *reinterpret_cast<const bf16x8*>(W1T + n * KP + ks * 32 + lq * 8);
    }

    f32x4 acc[4][4];
#pragma unroll
    for (int mt = 0; mt < 4; ++mt)
#pragma unroll
        for (int nt = 0; nt < 4; ++nt)
            acc[mt][nt] = (f32x4){0.f, 0.f, 0.f, 0.f};

#pragma unroll
    for (int mt = 0; mt < 4; ++mt) {
        bf16x8 af[5];
        const unsigned short* ap = At + (mt * 16 + lr) * LDA + lq * 8;
#pragma unroll
        for (int ks = 0; ks < 5; ++ks)
            af[ks] = *reinterpret_cast<const bf16x8*>(ap + ks * 32);
#pragma unroll
        for (int nt = 0; nt < 4; ++nt)
#pragma unroll
            for (int ks = 0; ks < 5; ++ks)
                acc[mt][nt] = __builtin_amdgcn_mfma_f32_16x16x32_bf16(
                    af[ks], bfr[nt][ks], acc[mt][nt], 0, 0, 0);
    }

    // ---- epilogue: attn[m] = sum_n relu(hidden+b1)*W2 ----
#pragma unroll
    for (int mt = 0; mt < 4; ++mt) {
#pragma unroll
        for (int r = 0; r < 4; ++r) {
            float s = 0.f;
#pragma unroll
            for (int nt = 0; nt < 4; ++nt) {
                float hv = acc[mt][nt][r] + b1v[nt];
                hv = fmaxf(hv, 0.f);
                s += hv * w2v[nt];
            }
            // reduce across the 16 col-lanes of this quad
            s += __shfl_xor(s, 1);
            s += __shfl_xor(s, 2);
            s += __shfl_xor(s, 4);
            s += __shfl_xor(s, 8);
            if (lr == 0) red[mt * 16 + lq * 4 + r][w] = s;
        }
    }
    __syncthreads();

    if (tid < BM) {
        const int row = rowBase + tid;
        const int b = row / H_SZ;
        float attn = red[tid][0] + red[tid][1] + red[tid][2] + red[tid][3];
        float e = (history[row] != target[b]) ? expf(attn) : 0.f;
        expA[row] = e;
        uOut[row] = u_lds[tid];
    }
}

// per-b: pred = sum_h expA*u / sqrt(sum_h expA); out = sigmoid(pred)
__global__ void finalize_kernel(const float* __restrict__ expA,
                                const float* __restrict__ uIn,
                                float* __restrict__ out)
{
    const int l = threadIdx.x & 63;
    const int w = threadIdx.x >> 6;
    const int b = blockIdx.x * 4 + w;
    const float* ea = expA + b * H_SZ;
    const float* uu = uIn + b * H_SZ;
    float se = 0.f, su = 0.f;
    for (int h = l; h < H_SZ; h += 64) {
        float e = ea[h];
        se += e;
        su += e * uu[h];
    }
#pragma unroll
    for (int off = 32; off; off >>= 1) {
        se += __shfl_xor(se, off);
        su += __shfl_xor(su, off);
    }
    if (l == 0) {
        float pred = su / sqrtf(se);
        out[b] = 1.f / (1.f + expf(-pred));
    }
}

extern "C" void kernel_launch(void* const* d_in, const int* in_sizes, int n_in,
                              void* d_out, int out_size, void* d_ws, size_t ws_size,
                              hipStream_t stream) {
    const int*   history = (const int*)d_in[0];
    const int*   target  = (const int*)d_in[1];
    // d_in[2] history_region, d_in[3] target_region: unused by reference
    const float* td      = (const float*)d_in[4];
    const float* eh      = (const float*)d_in[5];
    const float* et      = (const float*)d_in[6];
    const float* W1      = (const float*)d_in[7];
    const float* b1      = (const float*)d_in[8];
    const float* W2      = (const float*)d_in[9];
    const float* Wd      = (const float*)d_in[10];
    const float* bd      = (const float*)d_in[11];
    float* out = (float*)d_out;

    char* ws = (char*)d_ws;
    unsigned short* W1T = (unsigned short*)ws;                 // 256*160*2 = 81920 B
    float* expA = (float*)(ws + 81920);                        // BH*4 = 1638400 B
    float* u    = (float*)(ws + 81920 + 1638400);              // BH*4

    prep_w1t<<<KP * HID / 256, 256, 0, stream>>>(W1, W1T);
    attn_kernel<<<BH / BM, 256, 0, stream>>>(history, target, td, eh, et, W1T,
                                             b1, W2, Wd, bd, expA, u);
    finalize_kernel<<<B_SZ / 4, 256, 0, stream>>>(expA, u, out);
}

// Round 2
// 121.167 us; speedup vs baseline: 1.1793x; 1.1793x over previous
//
#include <hip/hip_runtime.h>
#include <hip/hip_bf16.h>

#define B_SZ 2048
#define H_SZ 200
#define BH (B_SZ * H_SZ)
#define EMB 128
#define HID 256
#define KP 160          // padded K (130 real + zero pad)
#define LDA 168         // LDS row stride in ushorts (bank-conflict pad, 336B)
#define BM 64           // rows per block

typedef short bf16x8 __attribute__((ext_vector_type(8)));
typedef float f32x4 __attribute__((ext_vector_type(4)));

__device__ __forceinline__ unsigned short bfc(float x) {
    // RNE float->bf16 (finite values only here)
    unsigned u = __float_as_uint(x);
    u += 0x7FFFu + ((u >> 16) & 1u);
    return (unsigned short)(u >> 16);
}
__device__ __forceinline__ float bf2f(unsigned short h) {
    return __uint_as_float(((unsigned)h) << 16);
}

// W1 [130][256] fp32 -> W1T [256][160] bf16, zero-padded K rows 130..159
__global__ void prep_w1t(const float* __restrict__ W1, unsigned short* __restrict__ W1T) {
    int i = blockIdx.x * 256 + threadIdx.x;      // 256*160 total
    int n = i / KP;
    int k = i - n * KP;
    float v = (k < 130) ? W1[k * HID + n] : 0.f;
    W1T[i] = bfc(v);
}

// embed_history fp32 -> bf16 table (halves gather bytes). 8 elems/thread.
__global__ void prep_ehb(const float* __restrict__ eh, unsigned short* __restrict__ ehb) {
    size_t t = (size_t)blockIdx.x * 256 + threadIdx.x;   // 1,600,000 threads
    const float4* src = (const float4*)eh + t * 2;
    float4 a = src[0], b = src[1];
    uint4 o;
    o.x = (unsigned)bfc(a.x) | ((unsigned)bfc(a.y) << 16);
    o.y = (unsigned)bfc(a.z) | ((unsigned)bfc(a.w) << 16);
    o.z = (unsigned)bfc(b.x) | ((unsigned)bfc(b.y) << 16);
    o.w = (unsigned)bfc(b.z) | ((unsigned)bfc(b.w) << 16);
    ((uint4*)ehb)[t] = o;
}

template<bool BF16E>
__global__ __launch_bounds__(512, 4) void attn_kernel(
    const int* __restrict__ history, const int* __restrict__ target,
    const float* __restrict__ td, const float* __restrict__ eh,
    const unsigned short* __restrict__ ehb,
    const float* __restrict__ et, const unsigned short* __restrict__ W1T,
    const float* __restrict__ b1, const float* __restrict__ W2,
    const float* __restrict__ Wd, const float* __restrict__ bd,
    float* __restrict__ expA, float* __restrict__ uOut)
{
    __shared__ __align__(16) unsigned short At[BM * LDA];
    __shared__ float u_lds[BM];
    __shared__ float red[BM][8];

    const int tid = threadIdx.x;
    const int rowBase = blockIdx.x * BM;

    // ---- build A tile: 8 threads/row, 16 elems each ----
    {
        const int m = tid >> 3;          // row within tile
        const int o = tid & 7;           // 16-elem chunk of EMB
        const int row = rowBase + m;
        const int b = row / H_SZ;
        const int idx = history[row];
        const int tgt = target[b];

        // hoisted loads: h (2x16B from bf16 table or 4x16B fp32), t (4x16B, L1-hot)
        float hv[16];
        if (BF16E) {
            const bf16x8* hp = (const bf16x8*)(ehb + (size_t)idx * EMB + o * 16);
            bf16x8 h0 = hp[0], h1 = hp[1];
#pragma unroll
            for (int i = 0; i < 8; ++i) {
                hv[i]     = bf2f((unsigned short)h0[i]);
                hv[8 + i] = bf2f((unsigned short)h1[i]);
            }
        } else {
            const float4* hp = (const float4*)(eh + (size_t)idx * EMB + o * 16);
            float4 a0 = hp[0], a1 = hp[1], a2 = hp[2], a3 = hp[3];
            hv[0]=a0.x; hv[1]=a0.y; hv[2]=a0.z; hv[3]=a0.w;
            hv[4]=a1.x; hv[5]=a1.y; hv[6]=a1.z; hv[7]=a1.w;
            hv[8]=a2.x; hv[9]=a2.y; hv[10]=a2.z; hv[11]=a2.w;
            hv[12]=a3.x; hv[13]=a3.y; hv[14]=a3.z; hv[15]=a3.w;
        }
        const float4* tp = (const float4*)(et + (size_t)tgt * EMB + o * 16);
        float4 t0 = tp[0], t1 = tp[1], t2 = tp[2], t3 = tp[3];
        float tv[16] = {t0.x,t0.y,t0.z,t0.w, t1.x,t1.y,t1.z,t1.w,
                        t2.x,t2.y,t2.z,t2.w, t3.x,t3.y,t3.z,t3.w};

        float su = 0.f;
        unsigned pk[8];
#pragma unroll
        for (int i = 0; i < 8; ++i) {
            float p0 = hv[2*i] * tv[2*i];
            float p1 = hv[2*i+1] * tv[2*i+1];
            su += p0 + p1;
            pk[i] = (unsigned)bfc(p0) | ((unsigned)bfc(p1) << 16);
        }
        uint4* dst = (uint4*)(At + m * LDA + o * 16);
        dst[0] = make_uint4(pk[0], pk[1], pk[2], pk[3]);
        dst[1] = make_uint4(pk[4], pk[5], pk[6], pk[7]);

        // u = sum_k (h*t)[k], reduced over the 8 threads of this row
        su += __shfl_xor(su, 1);
        su += __shfl_xor(su, 2);
        su += __shfl_xor(su, 4);
        if (o == 0) {
            u_lds[m] = su;
            // dist layer: sigmoid(1000*td @ Wd + bd)
            float x0 = td[(size_t)row * 2 + 0] * 1000.f;
            float x1 = td[(size_t)row * 2 + 1] * 1000.f;
            float d0 = x0 * Wd[0] + x1 * Wd[2] + bd[0];
            float d1 = x0 * Wd[1] + x1 * Wd[3] + bd[1];
            d0 = 1.f / (1.f + expf(-d0));
            d1 = 1.f / (1.f + expf(-d1));
            At[m * LDA + 128] = bfc(d0);
            At[m * LDA + 129] = bfc(d1);
        } else if (o == 1) {
            unsigned* z = (unsigned*)(At + m * LDA + 130);   // 4B-aligned (260B)
#pragma unroll
            for (int k = 0; k < 15; ++k) z[k] = 0;           // elems 130..159
        }
    }
    __syncthreads();

    // ---- MFMA: hidden = A @ W1; 8 waves each own a 32-col strip, ks-outer ----
    const int l  = tid & 63;
    const int w  = tid >> 6;
    const int lr = l & 15;
    const int lq = l >> 4;

    float b1v[2], w2v[2];
#pragma unroll
    for (int nt = 0; nt < 2; ++nt) {
        const int n = w * 32 + nt * 16 + lr;
        b1v[nt] = b1[n];
        w2v[nt] = W2[n];
    }

    f32x4 acc[4][2];
#pragma unroll
    for (int mt = 0; mt < 4; ++mt)
#pragma unroll
        for (int nt = 0; nt < 2; ++nt)
            acc[mt][nt] = (f32x4){0.f, 0.f, 0.f, 0.f};

#pragma unroll
    for (int ks = 0; ks < 5; ++ks) {
        bf16x8 bfr[2];
#pragma unroll
        for (int nt = 0; nt < 2; ++nt)
            bfr[nt] = *reinterpret_cast<const bf16x8*>(
                W1T + (w * 32 + nt * 16 + lr) * KP + ks * 32 + lq * 8);
#pragma unroll
        for (int mt = 0; mt < 4; ++mt) {
            bf16x8 af = *reinterpret_cast<const bf16x8*>(
                At + (mt * 16 + lr) * LDA + ks * 32 + lq * 8);
#pragma unroll
            for (int nt = 0; nt < 2; ++nt)
                acc[mt][nt] = __builtin_amdgcn_mfma_f32_16x16x32_bf16(
                    af, bfr[nt], acc[mt][nt], 0, 0, 0);
        }
    }

    // ---- epilogue: attn[m] = sum_n relu(hidden+b1)*W2 ----
#pragma unroll
    for (int mt = 0; mt < 4; ++mt) {
#pragma unroll
        for (int r = 0; r < 4; ++r) {
            float s = 0.f;
#pragma unroll
            for (int nt = 0; nt < 2; ++nt) {
                float hvv = acc[mt][nt][r] + b1v[nt];
                hvv = fmaxf(hvv, 0.f);
                s += hvv * w2v[nt];
            }
            s += __shfl_xor(s, 1);
            s += __shfl_xor(s, 2);
            s += __shfl_xor(s, 4);
            s += __shfl_xor(s, 8);
            if (lr == 0) red[mt * 16 + lq * 4 + r][w] = s;
        }
    }
    __syncthreads();

    if (tid < BM) {
        const int row = rowBase + tid;
        const int b = row / H_SZ;
        float attn = 0.f;
#pragma unroll
        for (int ww = 0; ww < 8; ++ww) attn += red[tid][ww];
        float e = (history[row] != target[b]) ? expf(attn) : 0.f;
        expA[row] = e;
        uOut[row] = u_lds[tid];
    }
}

// per-b: pred = sum_h expA*u / sqrt(sum_h expA); out = sigmoid(pred)
__global__ void finalize_kernel(const float* __restrict__ expA,
                                const float* __restrict__ uIn,
                                float* __restrict__ out)
{
    const int l = threadIdx.x & 63;
    const int w = threadIdx.x >> 6;
    const int b = blockIdx.x * 4 + w;
    const float* ea = expA + b * H_SZ;
    const float* uu = uIn + b * H_SZ;
    float se = 0.f, su = 0.f;
    for (int h = l; h < H_SZ; h += 64) {
        float e = ea[h];
        se += e;
        su += e * uu[h];
    }
#pragma unroll
    for (int off = 32; off; off >>= 1) {
        se += __shfl_xor(se, off);
        su += __shfl_xor(su, off);
    }
    if (l == 0) {
        float pred = su / sqrtf(se);
        out[b] = 1.f / (1.f + expf(-pred));
    }
}

extern "C" void kernel_launch(void* const* d_in, const int* in_sizes, int n_in,
                              void* d_out, int out_size, void* d_ws, size_t ws_size,
                              hipStream_t stream) {
    const int*   history = (const int*)d_in[0];
    const int*   target  = (const int*)d_in[1];
    // d_in[2] history_region, d_in[3] target_region: unused by reference
    const float* td      = (const float*)d_in[4];
    const float* eh      = (const float*)d_in[5];
    const float* et      = (const float*)d_in[6];
    const float* W1      = (const float*)d_in[7];
    const float* b1      = (const float*)d_in[8];
    const float* W2      = (const float*)d_in[9];
    const float* Wd      = (const float*)d_in[10];
    const float* bd      = (const float*)d_in[11];
    float* out = (float*)d_out;

    char* ws = (char*)d_ws;
    unsigned short* W1T = (unsigned short*)ws;                 // 81,920 B
    float* expA = (float*)(ws + 81920);                        // 1,638,400 B
    float* u    = (float*)(ws + 81920 + 1638400);              // 1,638,400 B
    unsigned short* ehb = (unsigned short*)(ws + 81920 + 2 * 1638400);  // 25,600,000 B
    const size_t need_bf16 = 81920 + 2ull * 1638400 + 25600000ull;
    const bool useBf16 = ws_size >= need_bf16;

    prep_w1t<<<KP * HID / 256, 256, 0, stream>>>(W1, W1T);
    if (useBf16) {
        prep_ehb<<<1600000 / 256, 256, 0, stream>>>(eh, ehb);
        attn_kernel<true><<<BH / BM, 512, 0, stream>>>(history, target, td, eh, ehb,
                                                       et, W1T, b1, W2, Wd, bd, expA, u);
    } else {
        attn_kernel<false><<<BH / BM, 512, 0, stream>>>(history, target, td, eh, ehb,
                                                        et, W1T, b1, W2, Wd, bd, expA, u);
    }
    finalize_kernel<<<B_SZ / 4, 256, 0, stream>>>(expA, u, out);
}

// Round 3
// 109.820 us; speedup vs baseline: 1.3011x; 1.1033x over previous
//
#include <hip/hip_runtime.h>
#include <hip/hip_bf16.h>

#define B_SZ 2048
#define H_SZ 200
#define EMB 128
#define HID 256

typedef short bf16x8 __attribute__((ext_vector_type(8)));
typedef float f32x4 __attribute__((ext_vector_type(4)));

#define WAIT_VM(n) asm volatile("s_waitcnt vmcnt(" #n ")" ::: "memory")
#define WAIT_LGKM  asm volatile("s_waitcnt lgkmcnt(0)" ::: "memory")
#define BAR        asm volatile("s_barrier" ::: "memory")

__device__ __forceinline__ unsigned short bfc(float x) {
    unsigned u = __float_as_uint(x);
    u += 0x7FFFu + ((u >> 16) & 1u);
    return (unsigned short)(u >> 16);
}
__device__ __forceinline__ float bf2f(unsigned short h) {
    return __uint_as_float(((unsigned)h) << 16);
}

// W1 [130][256] fp32 -> W1TB [256][128] bf16 (k<128 rows only; dist rows handled in epilogue)
__global__ void prep_w1t(const float* __restrict__ W1, unsigned short* __restrict__ W1TB) {
    int i = blockIdx.x * 256 + threadIdx.x;      // 256*128
    int n = i >> 7;
    int k = i & 127;
    W1TB[i] = bfc(W1[k * HID + n]);
}

// embed_history fp32 -> bf16 table
__global__ void prep_ehb(const float* __restrict__ eh, unsigned short* __restrict__ ehb) {
    size_t t = (size_t)blockIdx.x * 256 + threadIdx.x;   // 1,600,000 threads
    const float4* src = (const float4*)eh + t * 2;
    float4 a = src[0], b = src[1];
    uint4 o;
    o.x = (unsigned)bfc(a.x) | ((unsigned)bfc(a.y) << 16);
    o.y = (unsigned)bfc(a.z) | ((unsigned)bfc(a.w) << 16);
    o.z = (unsigned)bfc(b.x) | ((unsigned)bfc(b.y) << 16);
    o.w = (unsigned)bfc(b.z) | ((unsigned)bfc(b.w) << 16);
    ((uint4*)ehb)[t] = o;
}

__device__ __forceinline__ void gld_lds16(const unsigned short* g, unsigned short* l) {
    __builtin_amdgcn_global_load_lds(
        (const __attribute__((address_space(1))) void*)(g),
        (__attribute__((address_space(3))) void*)(l),
        16, 0, 0);
}

// One block per b. A = gathered bf16 h-rows (quad-buffered DMA, XOR-swizzled),
// B_b = diag(t) @ W1[:128] in registers. Epilogue adds dist rank-2 term, relu,
// *W2, cross-wave reduce; final phase does mask/exp/u/pool/sigmoid in-block.
__global__ __launch_bounds__(512, 4) void attn_kernel(
    const int* __restrict__ history, const int* __restrict__ target,
    const float* __restrict__ td, const unsigned short* __restrict__ ehb,
    const float* __restrict__ et, const unsigned short* __restrict__ W1TB,
    const float* __restrict__ b1, const float* __restrict__ W2,
    const float* __restrict__ W1, const float* __restrict__ Wd,
    const float* __restrict__ bd, float* __restrict__ out)
{
    __shared__ __align__(16) unsigned short Abuf[4][64][128];  // 64 KB, chunk-swizzled
    __shared__ float red[4][64][9];                            // per-wave attn partials
    __shared__ float2 dpack[256];                              // dist d0,d1 per row
    __shared__ int idxs[256];
    __shared__ float t_f32[EMB];
    __shared__ float finred[16];

    const int tid = threadIdx.x;
    const int b   = blockIdx.x;
    const int tgt = target[b];

    // ---- phase 0: stage t row, dist, history idx ----
    if (tid < 128) t_f32[tid] = et[(size_t)tgt * EMB + tid];
    {
        const int m0 = tid - 128;
        if (m0 >= 0 && m0 < H_SZ) {
            const int row = b * H_SZ + m0;
            idxs[m0] = history[row];
            float x0 = td[(size_t)row * 2 + 0] * 1000.f;
            float x1 = td[(size_t)row * 2 + 1] * 1000.f;
            float d0 = x0 * Wd[0] + x1 * Wd[2] + bd[0];
            float d1 = x0 * Wd[1] + x1 * Wd[3] + bd[1];
            d0 = 1.f / (1.f + expf(-d0));
            d1 = 1.f / (1.f + expf(-d1));
            dpack[m0] = make_float2(d0, d1);
        } else if (m0 >= H_SZ && m0 < 128 + 128) {
            // zero pad rows 200..255 (avoid NaN garbage in unused epilogue lanes)
            if (m0 < 256) dpack[m0] = make_float2(0.f, 0.f);
        }
    }
    WAIT_LGKM; BAR;

    const int l  = tid & 63;
    const int w  = tid >> 6;
    const int lr = l & 15;
    const int lq = l >> 4;

    // ---- B_b = diag(t) @ W1[:,:128]  (bf16 frags in regs) + scalar preloads ----
    bf16x8 bfrB[2][4];
    float b1v[2], w2v[2], wd0[2], wd1[2];
#pragma unroll
    for (int nt = 0; nt < 2; ++nt) {
        const int n = w * 32 + nt * 16 + lr;
        b1v[nt] = b1[n];
        w2v[nt] = W2[n];
        wd0[nt] = W1[128 * HID + n];
        wd1[nt] = W1[129 * HID + n];
#pragma unroll
        for (int ks = 0; ks < 4; ++ks) {
            const int k0 = ks * 32 + lq * 8;
            bf16x8 wv = *reinterpret_cast<const bf16x8*>(W1TB + n * EMB + k0);
            bf16x8 o;
#pragma unroll
            for (int j = 0; j < 8; ++j) {
                float f = bf2f((unsigned short)wv[j]) * t_f32[k0 + j];
                o[j] = (short)bfc(f);
            }
            bfrB[nt][ks] = o;
        }
    }

    // drain all compiler vmem so hand-counted vmcnt below is exact
    WAIT_VM(0);

    // ---- issue ALL gather DMAs (quad buffer, 2 insts/wave/tile) ----
    // LDS[r][c] = H[r][c ^ (r&7)]  (16B chunks), linear dest per rule 21
#pragma unroll
    for (int t = 0; t < 3; ++t) {
#pragma unroll
        for (int j = 0; j < 2; ++j) {
            const int rd = w * 8 + j * 4 + (l >> 4);          // tile-local row
            const int cc = (l & 15) ^ (rd & 7);
            const unsigned short* g = ehb + (size_t)idxs[t * 64 + rd] * EMB + cc * 8;
            gld_lds16(g, &Abuf[t][w * 8 + j * 4][0]);
        }
    }
    // tile 3: 8 real rows; every wave issues the same 2 insts (identical data)
#pragma unroll
    for (int j = 0; j < 2; ++j) {
        const int rd = j * 4 + (l >> 4);
        const int cc = (l & 15) ^ (rd & 7);
        const unsigned short* g = ehb + (size_t)idxs[192 + rd] * EMB + cc * 8;
        gld_lds16(g, &Abuf[3][j * 4][0]);
    }

    // ---- main loop: counted vmcnt, raw barrier, MFMA + epilogue per tile ----
#pragma unroll
    for (int t = 0; t < 4; ++t) {
        if (t == 0)      WAIT_VM(6);
        else if (t == 1) WAIT_VM(4);
        else if (t == 2) WAIT_VM(2);
        else             WAIT_VM(0);
        WAIT_LGKM;
        BAR;

        const int mc = (t == 3) ? 1 : 4;
        const unsigned short* A = &Abuf[t][0][0];

        f32x4 acc[4][2];
#pragma unroll
        for (int mt = 0; mt < 4; ++mt)
#pragma unroll
            for (int nt = 0; nt < 2; ++nt)
                acc[mt][nt] = (f32x4){0.f, 0.f, 0.f, 0.f};

#pragma unroll
        for (int ks = 0; ks < 4; ++ks) {
#pragma unroll
            for (int mt = 0; mt < 4; ++mt) if (mt < mc) {
                const int ar = mt * 16 + lr;
                const bf16x8 af = *reinterpret_cast<const bf16x8*>(
                    A + ar * EMB + (((ks * 4 + lq) ^ (ar & 7)) * 8));
                acc[mt][0] = __builtin_amdgcn_mfma_f32_16x16x32_bf16(af, bfrB[0][ks], acc[mt][0], 0, 0, 0);
                acc[mt][1] = __builtin_amdgcn_mfma_f32_16x16x32_bf16(af, bfrB[1][ks], acc[mt][1], 0, 0, 0);
            }
        }

        // epilogue: attn partial for this wave's 32 cols
#pragma unroll
        for (int mt = 0; mt < 4; ++mt) if (mt < mc) {
#pragma unroll
            for (int r = 0; r < 4; ++r) {
                const int mrow = mt * 16 + lq * 4 + r;        // tile-local
                float2 d = dpack[t * 64 + mrow];
                float s = 0.f;
#pragma unroll
                for (int nt = 0; nt < 2; ++nt) {
                    float hv = acc[mt][nt][r] + b1v[nt] + d.x * wd0[nt] + d.y * wd1[nt];
                    hv = fmaxf(hv, 0.f);
                    s += hv * w2v[nt];
                }
                s += __shfl_xor(s, 1);
                s += __shfl_xor(s, 2);
                s += __shfl_xor(s, 4);
                s += __shfl_xor(s, 8);
                if (lr == 0) red[t][mrow][w] = s;
            }
        }
    }

    WAIT_LGKM; BAR;

    // ---- final: attn -> exp/mask, u = h.t from LDS A, pooled sigmoid ----
    float se = 0.f, su = 0.f;
    if (tid < H_SZ) {
        const int tt = tid >> 6, mrow = tid & 63;
        float attn = 0.f;
#pragma unroll
        for (int ww = 0; ww < 8; ++ww) attn += red[tt][mrow][ww];
        const unsigned short* Arow = &Abuf[tt][mrow][0];
        float u = 0.f;
#pragma unroll
        for (int c = 0; c < 16; ++c) {
            bf16x8 hv = *reinterpret_cast<const bf16x8*>(Arow + ((c ^ (mrow & 7)) * 8));
#pragma unroll
            for (int j = 0; j < 8; ++j)
                u += bf2f((unsigned short)hv[j]) * t_f32[c * 8 + j];
        }
        float e = (idxs[tid] != tgt) ? expf(attn) : 0.f;
        se = e;
        su = e * u;
    }
#pragma unroll
    for (int off = 1; off < 64; off <<= 1) {
        se += __shfl_xor(se, off);
        su += __shfl_xor(su, off);
    }
    if (l == 0) { finred[w * 2] = se; finred[w * 2 + 1] = su; }
    WAIT_LGKM; BAR;
    if (tid == 0) {
        float SE = 0.f, SU = 0.f;
#pragma unroll
        for (int ww = 0; ww < 8; ++ww) { SE += finred[2 * ww]; SU += finred[2 * ww + 1]; }
        out[b] = 1.f / (1.f + expf(-SU / sqrtf(SE)));
    }
}

extern "C" void kernel_launch(void* const* d_in, const int* in_sizes, int n_in,
                              void* d_out, int out_size, void* d_ws, size_t ws_size,
                              hipStream_t stream) {
    const int*   history = (const int*)d_in[0];
    const int*   target  = (const int*)d_in[1];
    const float* td      = (const float*)d_in[4];
    const float* eh      = (const float*)d_in[5];
    const float* et      = (const float*)d_in[6];
    const float* W1      = (const float*)d_in[7];
    const float* b1      = (const float*)d_in[8];
    const float* W2      = (const float*)d_in[9];
    const float* Wd      = (const float*)d_in[10];
    const float* bd      = (const float*)d_in[11];
    float* out = (float*)d_out;

    char* ws = (char*)d_ws;
    unsigned short* W1TB = (unsigned short*)ws;            // 256*128*2 = 65,536 B
    unsigned short* ehb  = (unsigned short*)(ws + 65536);  // 100000*128*2 = 25,600,000 B

    prep_w1t<<<HID * EMB / 256, 256, 0, stream>>>(W1, W1TB);
    prep_ehb<<<1600000 / 256, 256, 0, stream>>>(eh, ehb);
    attn_kernel<<<B_SZ, 512, 0, stream>>>(history, target, td, ehb, et, W1TB,
                                          b1, W2, W1, Wd, bd, out);
}